// Round 4
// baseline (378.444 us; speedup 1.0000x reference)
//
#include <hip/hip_runtime.h>
#include <cstddef>
#include <cstdint>

// MinGRU: g/v/d = x@W{g,v,d}^T + b; xs = sigmoid(g)*tanh(v); a = 0.001+0.998*sigmoid(d)
// h_t = a_t*h_{t-1} + xs_t (causal scan over S). Output h [B,S,D] f32.
// B=4, S=4096, D=1024.
// R4: GEMM BK=64 (2x32 sub-tiles per barrier pair); scans at 1024 blocks
// (CLEN=8, 8ch/thread); scan2 with transposed P/H for vectorized chains.

typedef _Float16 f16;
typedef f16 f16x8 __attribute__((ext_vector_type(8)));
typedef float f32x4 __attribute__((ext_vector_type(4)));

#define S_LEN 4096
#define D_DIM 1024
#define B_DIM 4
#define M_TOT (B_DIM * S_LEN)  // 16384
#define N_TOT (3 * D_DIM)      // 3072
#define K_TOT D_DIM            // 1024

#define CLEN 8
#define CPB (S_LEN / CLEN)   // 512 chunks per batch
#define NCHUNK (B_DIM * CPB) // 2048

// ---------------- merged f32 -> f16 convert: x then Wg|Wv|Wd ----------------
__device__ __forceinline__ void cvt8(const float* s, f16* d) {
  f32x4 a = *(const f32x4*)s;
  f32x4 b = *(const f32x4*)(s + 4);
  f16x8 o;
  o[0] = (f16)a[0]; o[1] = (f16)a[1]; o[2] = (f16)a[2]; o[3] = (f16)a[3];
  o[4] = (f16)b[0]; o[5] = (f16)b[1]; o[6] = (f16)b[2]; o[7] = (f16)b[3];
  *(f16x8*)d = o;
}

__global__ void cvt_all_kernel(const float* __restrict__ x, const float* __restrict__ w0,
                               const float* __restrict__ w1, const float* __restrict__ w2,
                               f16* __restrict__ Ah, f16* __restrict__ Bh) {
  int i = (blockIdx.x * 256 + threadIdx.x) * 8;
  if (i < M_TOT * K_TOT) {
    cvt8(x + i, Ah + i);
  } else {
    int w = i - M_TOT * K_TOT;
    int sel = w >> 20;
    int loc = w & 1048575;
    const float* s = (sel == 0) ? w0 : (sel == 1) ? w1 : w2;
    cvt8(s + loc, Bh + w);
  }
}

// ---------------- GEMM: C[M,N] = A[M,K] * Bt[N,K]^T, fp16 in, fp16 out ----------------
#define BM 128
#define BN 128
#define CT_PITCH 136  // halves; epilogue tile row stride (16B aligned)

__device__ __forceinline__ void gl_lds16(const void* g, void* l) {
  __builtin_amdgcn_global_load_lds((const __attribute__((address_space(1))) void*)g,
                                   (__attribute__((address_space(3))) void*)l, 16, 0, 0);
}

__global__ __launch_bounds__(256) void gemm_f16_kernel(const f16* __restrict__ A,
                                                       const f16* __restrict__ Bt,
                                                       f16* __restrict__ C) {
  // staging: As0|As1 (2x8KB) + Bs0|Bs1 (2x8KB) = 32 KB; epilogue overlays 34 KB
  __shared__ __attribute__((aligned(16))) char smem[BM * CT_PITCH * 2];
  f16* As = (f16*)smem;        // [2][128][32] halves
  f16* Bs = As + 8192;         // [2][128][32] halves
  const int tid = threadIdx.x;
  const int lane = tid & 63;
  const int wave = tid >> 6;
  const int m0 = blockIdx.y * BM;
  const int n0 = blockIdx.x * BN;

  const int srow = tid >> 2;       // 0..63
  const int scol = (tid & 3) * 8;  // half index within 32-half row
  const f16* aG0 = A + (size_t)(m0 + srow) * K_TOT + scol;
  const f16* aG1 = A + (size_t)(m0 + srow + 64) * K_TOT + scol;
  const f16* bG0 = Bt + (size_t)(n0 + srow) * K_TOT + scol;
  const f16* bG1 = Bt + (size_t)(n0 + srow + 64) * K_TOT + scol;
  f16* aL0 = As + tid * 8;
  f16* aL1 = As + 2048 + tid * 8;
  f16* aL2 = As + 4096 + tid * 8;
  f16* aL3 = As + 6144 + tid * 8;
  f16* bL0 = Bs + tid * 8;
  f16* bL1 = Bs + 2048 + tid * 8;
  f16* bL2 = Bs + 4096 + tid * 8;
  f16* bL3 = Bs + 6144 + tid * 8;

  const int wm = (wave >> 1) * 64;
  const int wn = (wave & 1) * 64;
  const int lm = lane & 15;
  const int kq = (lane >> 4) * 8;

  f32x4 acc[4][4] = {};

  for (int k0 = 0; k0 < K_TOT; k0 += 64) {
    // stage two BK=32 sub-tiles per barrier pair
    gl_lds16(aG0 + k0, aL0);
    gl_lds16(aG1 + k0, aL1);
    gl_lds16(aG0 + k0 + 32, aL2);
    gl_lds16(aG1 + k0 + 32, aL3);
    gl_lds16(bG0 + k0, bL0);
    gl_lds16(bG1 + k0, bL1);
    gl_lds16(bG0 + k0 + 32, bL2);
    gl_lds16(bG1 + k0 + 32, bL3);
    __syncthreads();  // drains vmcnt -> staging visible
#pragma unroll
    for (int h = 0; h < 2; ++h) {
      const f16* as = As + h * 4096;
      const f16* bs = Bs + h * 4096;
      f16x8 af[4], bf[4];
#pragma unroll
      for (int i = 0; i < 4; ++i)
        af[i] = *(const f16x8*)&as[(wm + i * 16 + lm) * 32 + kq];
#pragma unroll
      for (int j = 0; j < 4; ++j)
        bf[j] = *(const f16x8*)&bs[(wn + j * 16 + lm) * 32 + kq];
#pragma unroll
      for (int i = 0; i < 4; ++i)
#pragma unroll
        for (int j = 0; j < 4; ++j)
          acc[i][j] = __builtin_amdgcn_mfma_f32_16x16x32_f16(af[i], bf[j], acc[i][j], 0, 0, 0);
    }
    __syncthreads();  // protect LDS before next stage / epilogue overlay
  }

  // epilogue: acc -> LDS tile (C/D layout: col=lane&15, row=(lane>>4)*4+reg),
  // then coalesced f16x8 global stores.
  f16* Ct = (f16*)smem;
  const int r0 = wm + (lane >> 4) * 4;
  const int c0 = wn + (lane & 15);
#pragma unroll
  for (int i = 0; i < 4; ++i)
#pragma unroll
    for (int j = 0; j < 4; ++j)
#pragma unroll
      for (int r = 0; r < 4; ++r)
        Ct[(r0 + i * 16 + r) * CT_PITCH + c0 + j * 16] = (f16)acc[i][j][r];
  __syncthreads();
#pragma unroll
  for (int p = 0; p < 8; ++p) {
    int row = p * 16 + (tid >> 4);
    int col = (tid & 15) * 8;
    *(f16x8*)(C + (size_t)(m0 + row) * N_TOT + n0 + col) =
        *(const f16x8*)&Ct[row * CT_PITCH + col];
  }
}

// ---------------- scan pass 1: activations + per-chunk local scan ----------------
// thread: 8 channels x 8 timesteps; u = [ck:9][b:2][cg:7], 262144 threads.
// P/H stored TRANSPOSED: P[(b*1024+ch)*CPB + ck] for fast scan2 chains.
__global__ void scan1_kernel(const f16* __restrict__ G, const float* __restrict__ bg,
                             const float* __restrict__ bv, const float* __restrict__ bd,
                             f16* __restrict__ xsA, f16* __restrict__ aA,
                             float* __restrict__ P, float* __restrict__ H) {
  const int u = blockIdx.x * 256 + threadIdx.x;
  const int cg = u & 127;
  const int b = (u >> 7) & 3;
  const int ck = u >> 9;  // 0..511
  const int ch = cg * 8;
  float vbg[8], vbv[8], vbd[8];
  *(f32x4*)vbg = *(const f32x4*)(bg + ch); *(f32x4*)(vbg + 4) = *(const f32x4*)(bg + ch + 4);
  *(f32x4*)vbv = *(const f32x4*)(bv + ch); *(f32x4*)(vbv + 4) = *(const f32x4*)(bv + ch + 4);
  *(f32x4*)vbd = *(const f32x4*)(bd + ch); *(f32x4*)(vbd + 4) = *(const f32x4*)(bd + ch + 4);
  float h[8] = {}, p[8] = {1.f, 1.f, 1.f, 1.f, 1.f, 1.f, 1.f, 1.f};
  const int t0 = ck * CLEN;
#pragma unroll
  for (int t = t0; t < t0 + CLEN; ++t) {
    const size_t m = (size_t)b * S_LEN + t;
    const f16* gp = G + m * N_TOT + ch;
    f16x8 g8 = *(const f16x8*)gp;
    f16x8 v8 = *(const f16x8*)(gp + D_DIM);
    f16x8 d8 = *(const f16x8*)(gp + 2 * D_DIM);
    f16x8 xs8, a8;
#pragma unroll
    for (int j = 0; j < 8; ++j) {
      float gg = (float)g8[j] + vbg[j];
      float vv = (float)v8[j] + vbv[j];
      float dd = (float)d8[j] + vbd[j];
      float sg = 1.f / (1.f + __expf(-gg));
      float tv = 1.f - 2.f / (__expf(2.f * vv) + 1.f);
      float sd = 1.f / (1.f + __expf(-dd));
      f16 xh = (f16)(sg * tv);
      f16 ah = (f16)(0.001f + 0.998f * sd);
      // use ROUNDED values so pass-3 recomposition is exactly consistent
      float xsr = (float)xh, avr = (float)ah;
      h[j] = avr * h[j] + xsr;
      p[j] *= avr;
      xs8[j] = xh;
      a8[j] = ah;
    }
    *(f16x8*)(xsA + m * D_DIM + ch) = xs8;
    *(f16x8*)(aA + m * D_DIM + ch) = a8;
  }
#pragma unroll
  for (int j = 0; j < 8; ++j) {
    const size_t tbase = (size_t)(b * D_DIM + ch + j) * CPB + ck;
    P[tbase] = p[j];
    H[tbase] = h[j];
  }
}

// ---------------- scan pass 2: chain carries across CPB chunks per (b,d) ----------------
// P/H transposed [bd][c] -> contiguous f32x4 chain loads. carry written [gs][d]
// (gs = b*CPB+c) so scan3 reads coalesced.
__global__ void scan2_kernel(const float* __restrict__ P, const float* __restrict__ H,
                             float* __restrict__ carry) {
  const int bd = blockIdx.x * 256 + threadIdx.x;  // 0..4095 = b*1024+d
  const int b = bd >> 10;
  const int d = bd & 1023;
  const float* Pp = P + (size_t)bd * CPB;
  const float* Hp = H + (size_t)bd * CPB;
  float h = 0.f;
  for (int c = 0; c < CPB; c += 4) {
    f32x4 p4 = *(const f32x4*)(Pp + c);
    f32x4 h4 = *(const f32x4*)(Hp + c);
    float* cp = carry + (size_t)(b * CPB + c) * D_DIM + d;
    cp[0] = h;          h = p4[0] * h + h4[0];
    cp[D_DIM] = h;      h = p4[1] * h + h4[1];
    cp[2 * D_DIM] = h;  h = p4[2] * h + h4[2];
    cp[3 * D_DIM] = h;  h = p4[3] * h + h4[3];
  }
}

// ---------------- scan pass 3: rescan with carry, write output ----------------
__global__ void scan3_kernel(const f16* __restrict__ xsA, const f16* __restrict__ aA,
                             const float* __restrict__ carry, float* __restrict__ out) {
  const int u = blockIdx.x * 256 + threadIdx.x;
  const int cg = u & 127;
  const int b = (u >> 7) & 3;
  const int ck = u >> 9;  // 0..511
  const int ch = cg * 8;
  const size_t base = (size_t)(b * CPB + ck) * D_DIM + ch;
  float h[8];
  *(f32x4*)h = *(const f32x4*)(carry + base);
  *(f32x4*)(h + 4) = *(const f32x4*)(carry + base + 4);
  const int t0 = ck * CLEN;
#pragma unroll
  for (int t = t0; t < t0 + CLEN; ++t) {
    const size_t m = (size_t)b * S_LEN + t;
    f16x8 xs8 = *(const f16x8*)(xsA + m * D_DIM + ch);
    f16x8 a8 = *(const f16x8*)(aA + m * D_DIM + ch);
#pragma unroll
    for (int j = 0; j < 8; ++j) h[j] = (float)a8[j] * h[j] + (float)xs8[j];
    float* op = out + m * D_DIM + ch;
    *(f32x4*)op = *(f32x4*)h;
    *(f32x4*)(op + 4) = *(f32x4*)(h + 4);
  }
}

extern "C" void kernel_launch(void* const* d_in, const int* in_sizes, int n_in,
                              void* d_out, int out_size, void* d_ws, size_t ws_size,
                              hipStream_t stream) {
  const float* x = (const float*)d_in[0];
  const float* Wg = (const float*)d_in[1];
  const float* bg = (const float*)d_in[2];
  const float* Wv = (const float*)d_in[3];
  const float* bv = (const float*)d_in[4];
  const float* Wd = (const float*)d_in[5];
  const float* bd = (const float*)d_in[6];
  float* out = (float*)d_out;

  // workspace layout (207,618,048 B total).
  // Ah region (0..33.5MB) is dead after the GEMM; P/H/carry (25.2 MB) overlay it.
  char* ws = (char*)d_ws;
  f16* Ah = (f16*)(ws);                     // 33,554,432 B (cvt -> gemm only)
  float* P = (float*)(ws);                  // NCHUNK*1024*4 = 8,388,608 B (overlay)
  float* H = (float*)(ws + 8388608);        // 8,388,608 B
  float* carry = (float*)(ws + 16777216);   // 8,388,608 B
  f16* Bh = (f16*)(ws + 33554432);          // 6,291,456 B
  f16* Gh = (f16*)(ws + 39845888);          // 100,663,296 B
  f16* xsA = (f16*)(ws + 140509184);        // 33,554,432 B
  f16* aA = (f16*)(ws + 174063616);         // 33,554,432 B

  cvt_all_kernel<<<9728, 256, 0, stream>>>(x, Wg, Wv, Wd, Ah, Bh);
  gemm_f16_kernel<<<dim3(N_TOT / BN, M_TOT / BM), 256, 0, stream>>>(Ah, Bh, Gh);
  scan1_kernel<<<1024, 256, 0, stream>>>(Gh, bg, bv, bd, xsA, aA, P, H);
  scan2_kernel<<<16, 256, 0, stream>>>(P, H, carry);
  scan3_kernel<<<1024, 256, 0, stream>>>(xsA, aA, carry, out);
}